// Round 1
// baseline (1502.328 us; speedup 1.0000x reference)
//
#include <hip/hip_runtime.h>
#include <hip/hip_bf16.h>
#include <math.h>

// Problem constants (fixed by setup_inputs)
#define BB 8
#define HH 56
#define WW 56
#define NN (HH*WW)          // 3136
#define CC 256
#define NH 8
#define CHH 32
#define NT (BB*NN)          // 25088
#define HID 128
#define MH 1024
#define SCALE 0.17677669529663687f   // 32^-0.5

// ---------------- CPE: depthwise 3x3 + bias + residual ----------------
__global__ __launch_bounds__(256) void cpe_kernel(
    const float* __restrict__ x, const float* __restrict__ w,
    const float* __restrict__ bias, float* __restrict__ out)
{
    const int c = threadIdx.x;
    const int n = blockIdx.x % NN;
    const int b = blockIdx.x / NN;
    const int y = n / WW, xx = n % WW;
    const float* xb = x + (size_t)b * NN * CC;
    float acc = bias[c] + xb[(size_t)n * CC + c];
    #pragma unroll
    for (int dy = -1; dy <= 1; ++dy) {
        int yy = y + dy; if (yy < 0 || yy >= HH) continue;
        #pragma unroll
        for (int dx = -1; dx <= 1; ++dx) {
            int x2 = xx + dx; if (x2 < 0 || x2 >= WW) continue;
            acc += w[c * 9 + (dy + 1) * 3 + (dx + 1)] *
                   xb[(size_t)(yy * WW + x2) * CC + c];
        }
    }
    out[((size_t)b * NN + n) * CC + c] = acc;
}

// ---------------- LayerNorm over C=256, wave-per-row ----------------
__global__ __launch_bounds__(256) void ln_kernel(
    const float* __restrict__ src, const float* __restrict__ g_all,
    const float* __restrict__ b_all, const int* __restrict__ dptr,
    float* __restrict__ dst)
{
    const int wid = threadIdx.x >> 6, lane = threadIdx.x & 63;
    const int row = blockIdx.x * 4 + wid;
    const int d = *dptr;
    const float* g = g_all + d * CC;
    const float* be = b_all + d * CC;
    const float* p = src + (size_t)row * CC;
    float4 v = *(const float4*)(p + lane * 4);
    float s = v.x + v.y + v.z + v.w;
    float sq = v.x*v.x + v.y*v.y + v.z*v.z + v.w*v.w;
    #pragma unroll
    for (int off = 1; off < 64; off <<= 1) {
        s  += __shfl_xor(s, off);
        sq += __shfl_xor(sq, off);
    }
    const float mean = s * (1.f / CC);
    const float var = sq * (1.f / CC) - mean * mean;
    const float rs = rsqrtf(var + 1e-5f);
    float4 g4 = *(const float4*)(g + lane * 4);
    float4 b4 = *(const float4*)(be + lane * 4);
    float4 o;
    o.x = (v.x - mean) * rs * g4.x + b4.x;
    o.y = (v.y - mean) * rs * g4.y + b4.y;
    o.z = (v.z - mean) * rs * g4.z + b4.z;
    o.w = (v.w - mean) * rs * g4.w + b4.w;
    *(float4*)(dst + (size_t)row * CC + lane * 4) = o;
}

// ---------------- tiled f32 GEMM: C = A[MxK] @ B[KxN] (+bias)(+gelu)(+res) ----
// EPI: 0 = none, 2 = bias+gelu, 3 = bias+residual
#define BM 64
#define BN 64
#define BK 16
template<int EPI>
__global__ __launch_bounds__(256) void gemm_f32(
    const float* __restrict__ A, const float* __restrict__ Bm,
    const float* __restrict__ bias, const float* __restrict__ res,
    float* __restrict__ C, int M, int N, int K)
{
    __shared__ float As[BK][BM];
    __shared__ float Bs[BK][BN];
    const int t = threadIdx.x;
    const int bm = blockIdx.y, bn = blockIdx.x;
    const int tm = t & 15, tn = t >> 4;
    const int arow = t & 63, ak4 = t >> 6;     // A load: row, k-group
    const int bkrow = t >> 4, bcol4 = t & 15;  // B load: k-row, col-group
    float acc[4][4] = {};
    const float* Ablk = A + (size_t)(bm * BM) * K;
    const float* Bblk = Bm + bn * BN;
    for (int kt = 0; kt < K; kt += BK) {
        float4 a  = *(const float4*)(Ablk + (size_t)arow * K + kt + ak4 * 4);
        float4 bv = *(const float4*)(Bblk + (size_t)(kt + bkrow) * N + bcol4 * 4);
        __syncthreads();
        As[ak4 * 4 + 0][arow] = a.x;
        As[ak4 * 4 + 1][arow] = a.y;
        As[ak4 * 4 + 2][arow] = a.z;
        As[ak4 * 4 + 3][arow] = a.w;
        *(float4*)(&Bs[bkrow][bcol4 * 4]) = bv;
        __syncthreads();
        #pragma unroll
        for (int kk = 0; kk < BK; ++kk) {
            float4 av = *(const float4*)(&As[kk][tm * 4]);
            float4 bw = *(const float4*)(&Bs[kk][tn * 4]);
            float aa[4] = {av.x, av.y, av.z, av.w};
            float bb[4] = {bw.x, bw.y, bw.z, bw.w};
            #pragma unroll
            for (int i = 0; i < 4; ++i)
                #pragma unroll
                for (int j = 0; j < 4; ++j)
                    acc[i][j] += aa[i] * bb[j];
        }
    }
    const int row0 = bm * BM + tm * 4;
    const int col0 = bn * BN + tn * 4;
    float bias4[4] = {0.f, 0.f, 0.f, 0.f};
    if (EPI >= 2) {
        float4 bv = *(const float4*)(bias + col0);
        bias4[0] = bv.x; bias4[1] = bv.y; bias4[2] = bv.z; bias4[3] = bv.w;
    }
    #pragma unroll
    for (int i = 0; i < 4; ++i) {
        size_t off = (size_t)(row0 + i) * N + col0;
        float o[4];
        #pragma unroll
        for (int j = 0; j < 4; ++j) {
            float v = acc[i][j] + bias4[j];
            if (EPI == 2) v = 0.5f * v * (1.f + erff(v * 0.70710678118654752f));
            o[j] = v;
        }
        if (EPI == 3) {
            float4 r = *(const float4*)(res + off);
            o[0] += r.x; o[1] += r.y; o[2] += r.z; o[3] += r.w;
        }
        float4 ov = {o[0], o[1], o[2], o[3]};
        *(float4*)(C + off) = ov;
    }
}

// ---------------- k-softmax over tokens + kv = k_sm^T @ v ----------------
// grid = B*NH blocks; 256 threads; thread t: ck = t&31, cv-group g = t>>5
__global__ __launch_bounds__(256) void kv_kernel(
    const float* __restrict__ qkv, float* __restrict__ kv)
{
    const int bh = blockIdx.x;
    const int b = bh >> 3, h = bh & 7;
    const int t = threadIdx.x;
    const int ck = t & 31, g = t >> 5;
    __shared__ float red[256];
    __shared__ float colmax[32];
    const float* kbase = qkv + (size_t)b * NN * 768 + 256 + h * 32;
    const float* vbase = qkv + (size_t)b * NN * 768 + 512 + h * 32;
    float m = -3.4e38f;
    for (int n = g; n < NN; n += 8) m = fmaxf(m, kbase[(size_t)n * 768 + ck]);
    red[t] = m;
    __syncthreads();
    if (t < 32) {
        float mm = red[t];
        #pragma unroll
        for (int i = 1; i < 8; ++i) mm = fmaxf(mm, red[i * 32 + t]);
        colmax[t] = mm;
    }
    __syncthreads();
    const float cmax = colmax[ck];
    float acc0 = 0.f, acc1 = 0.f, acc2 = 0.f, acc3 = 0.f, csum = 0.f;
    for (int n = 0; n < NN; ++n) {
        float e = __expf(kbase[(size_t)n * 768 + ck] - cmax);
        float4 v4 = *(const float4*)(vbase + (size_t)n * 768 + g * 4);
        acc0 += e * v4.x; acc1 += e * v4.y; acc2 += e * v4.z; acc3 += e * v4.w;
        csum += e;   // identical across g for same ck
    }
    const float inv = 1.f / csum;
    float4 o = {acc0 * inv, acc1 * inv, acc2 * inv, acc3 * inv};
    *(float4*)(kv + ((size_t)bh * 32 + ck) * 32 + g * 4) = o;
}

// ---------------- domain gating: da[b, h*32+ch], softmaxed over heads ------
__global__ __launch_bounds__(256) void da_kernel(
    const float* __restrict__ dl, const float* __restrict__ w1,
    const float* __restrict__ b1, const float* __restrict__ w2,
    const float* __restrict__ b2, float* __restrict__ da)
{
    const int b = blockIdx.x, t = threadIdx.x;
    __shared__ float r[HID];
    __shared__ float raw[CC];
    if (t < HID) {
        float s = b1[t];
        #pragma unroll
        for (int k = 0; k < 4; ++k) s += dl[b * 4 + k] * w1[k * HID + t];
        r[t] = fmaxf(s, 0.f);
    }
    __syncthreads();
    float s = b2[t];
    for (int j = 0; j < HID; ++j) s += r[j] * w2[j * CC + t];
    raw[t] = s;
    __syncthreads();
    const int ch = t & 31;
    float m = -3.4e38f;
    #pragma unroll
    for (int hh = 0; hh < NH; ++hh) m = fmaxf(m, raw[hh * 32 + ch]);
    float ssum = 0.f;
    #pragma unroll
    for (int hh = 0; hh < NH; ++hh) ssum += __expf(raw[hh * 32 + ch] - m);
    da[b * CC + t] = __expf(raw[t] - m) / ssum;
}

// ---------------- combine: factor_att + CRPE conv + gating ----------------
__global__ __launch_bounds__(256) void combine_kernel(
    const float* __restrict__ qkv, const float* __restrict__ kv,
    const float* __restrict__ da,
    const float* __restrict__ w3, const float* __restrict__ b3,
    const float* __restrict__ w5, const float* __restrict__ b5,
    const float* __restrict__ w7, const float* __restrict__ b7,
    float* __restrict__ out)
{
    const int c = threadIdx.x;
    const int n = blockIdx.x % NN, b = blockIdx.x / NN;
    const int y = n / WW, xx = n % WW;
    const int h = c >> 5, ch = c & 31;
    __shared__ float qrow[CC];
    const float* qkvrow = qkv + ((size_t)b * NN + n) * 768;
    qrow[c] = qkvrow[c];
    __syncthreads();
    // factor_att = q . kv
    const float* kvp = kv + (size_t)(b * NH + h) * 32 * 32 + ch;
    float fa = 0.f;
    #pragma unroll
    for (int ck = 0; ck < 32; ++ck) fa += qrow[h * 32 + ck] * kvp[ck * 32];
    // depthwise conv on v (window size per head group)
    int ks; const float* w; float cb;
    if (h < 2)      { ks = 3; w = w3 + c * 9;          cb = b3[c]; }
    else if (h < 5) { ks = 5; w = w5 + (c - 64) * 25;  cb = b5[c - 64]; }
    else            { ks = 7; w = w7 + (c - 160) * 49; cb = b7[c - 160]; }
    const int r = ks >> 1;
    float conv = cb;
    const float* vb = qkv + (size_t)b * NN * 768 + 512 + c;
    for (int dy = -r; dy <= r; ++dy) {
        int yy = y + dy; if (yy < 0 || yy >= HH) continue;
        for (int dx = -r; dx <= r; ++dx) {
            int x2 = xx + dx; if (x2 < 0 || x2 >= WW) continue;
            conv += w[(dy + r) * ks + (dx + r)] * vb[(size_t)(yy * WW + x2) * 768];
        }
    }
    const float qc = qrow[c];
    out[((size_t)b * NN + n) * CC + c] =
        da[b * CC + c] * (SCALE * fa + qc * conv);
}

// ---------------- launch ----------------
extern "C" void kernel_launch(void* const* d_in, const int* in_sizes, int n_in,
                              void* d_out, int out_size, void* d_ws, size_t ws_size,
                              hipStream_t stream)
{
    const float* x       = (const float*)d_in[0];
    const float* dlab    = (const float*)d_in[1];
    const float* cpe_w   = (const float*)d_in[2];
    const float* cpe_b   = (const float*)d_in[3];
    const float* ln1_g   = (const float*)d_in[4];
    const float* ln1_b   = (const float*)d_in[5];
    const float* qkv_w   = (const float*)d_in[6];
    const float* proj_w  = (const float*)d_in[7];
    const float* proj_b  = (const float*)d_in[8];
    const float* dl_w1   = (const float*)d_in[9];
    const float* dl_b1   = (const float*)d_in[10];
    const float* dl_w2   = (const float*)d_in[11];
    const float* dl_b2   = (const float*)d_in[12];
    const float* crpe_w3 = (const float*)d_in[13];
    const float* crpe_b3 = (const float*)d_in[14];
    const float* crpe_w5 = (const float*)d_in[15];
    const float* crpe_b5 = (const float*)d_in[16];
    const float* crpe_w7 = (const float*)d_in[17];
    const float* crpe_b7 = (const float*)d_in[18];
    const float* ln2_g   = (const float*)d_in[19];
    const float* ln2_b   = (const float*)d_in[20];
    const float* fc1_w   = (const float*)d_in[21];
    const float* fc1_b   = (const float*)d_in[22];
    const float* fc2_w   = (const float*)d_in[23];
    const float* fc2_b   = (const float*)d_in[24];
    const int*   dptr    = (const int*)d_in[27];

    float* ws = (float*)d_ws;
    float* out = (float*)d_out;

    // workspace layout (floats)
    const size_t SZ_X = (size_t)NT * CC;          // 6,422,528
    float* x1   = ws;                              // [NT,C]   (later: mlp hidden chunk)
    float* cur  = ws + SZ_X;                       // [NT,C]   (LN out / attn_in)
    float* qkv  = ws + 2 * SZ_X;                   // [NT,768]
    float* kvb  = ws + 2 * SZ_X + (size_t)NT * 768;            // [B,NH,32,32]
    float* dab  = kvb + (size_t)BB * NH * 32 * 32;             // [B,256]

    // 1. CPE
    hipLaunchKernelGGL(cpe_kernel, dim3(NT), dim3(256), 0, stream,
                       x, cpe_w, cpe_b, x1);
    // 2. domain gating (independent)
    hipLaunchKernelGGL(da_kernel, dim3(BB), dim3(256), 0, stream,
                       dlab, dl_w1, dl_b1, dl_w2, dl_b2, dab);
    // 3. LN1
    hipLaunchKernelGGL(ln_kernel, dim3(NT / 4), dim3(256), 0, stream,
                       x1, ln1_g, ln1_b, dptr, cur);
    // 4. qkv GEMM  [NT,256]@[256,768]
    hipLaunchKernelGGL(gemm_f32<0>, dim3(768 / BN, NT / BM), dim3(256), 0, stream,
                       cur, qkv_w, nullptr, nullptr, qkv, NT, 768, CC);
    // 5. token-softmax + kv
    hipLaunchKernelGGL(kv_kernel, dim3(BB * NH), dim3(256), 0, stream, qkv, kvb);
    // 6. combine (factor_att + crpe + gating) -> attn_in in `cur`
    hipLaunchKernelGGL(combine_kernel, dim3(NT), dim3(256), 0, stream,
                       qkv, kvb, dab, crpe_w3, crpe_b3, crpe_w5, crpe_b5,
                       crpe_w7, crpe_b7, cur);
    // 7. proj GEMM + bias + residual(x1) -> x2 in d_out
    hipLaunchKernelGGL(gemm_f32<3>, dim3(CC / BN, NT / BM), dim3(256), 0, stream,
                       cur, proj_w, proj_b, x1, out, NT, CC, CC);
    // 8. LN2 -> cur
    hipLaunchKernelGGL(ln_kernel, dim3(NT / 4), dim3(256), 0, stream,
                       out, ln2_g, ln2_b, dptr, cur);
    // 9. MLP in 4 M-chunks (hidden buffer reuses x1 region)
    const int MCH = NT / 4;   // 6272
    for (int cidx = 0; cidx < 4; ++cidx) {
        const float* curc = cur + (size_t)cidx * MCH * CC;
        float* outc = out + (size_t)cidx * MCH * CC;
        hipLaunchKernelGGL(gemm_f32<2>, dim3(MH / BN, MCH / BM), dim3(256), 0, stream,
                           curc, fc1_w, fc1_b, nullptr, x1, MCH, MH, CC);
        hipLaunchKernelGGL(gemm_f32<3>, dim3(CC / BN, MCH / BM), dim3(256), 0, stream,
                           x1, fc2_w, fc2_b, outc, outc, MCH, CC, MH);
    }
}

// Round 2
// 922.705 us; speedup vs baseline: 1.6282x; 1.6282x over previous
//
#include <hip/hip_runtime.h>
#include <hip/hip_bf16.h>
#include <math.h>

// Problem constants (fixed by setup_inputs)
#define BB 8
#define HH 56
#define WW 56
#define NN (HH*WW)          // 3136
#define CC 256
#define NH 8
#define NT (BB*NN)          // 25088
#define HID 128
#define MH 1024
#define SCALE 0.17677669529663687f   // 32^-0.5

typedef __attribute__((ext_vector_type(8))) short bf16x8;
typedef __attribute__((ext_vector_type(4))) float f32x4;

__device__ __forceinline__ ushort f2bf(float f) {
    __hip_bfloat16 h = __float2bfloat16(f);
    return *(ushort*)&h;
}

__device__ __forceinline__ void gload16(const void* g, void* s) {
    __builtin_amdgcn_global_load_lds(
        (const __attribute__((address_space(1))) void*)g,
        (__attribute__((address_space(3))) void*)s, 16, 0, 0);
}

// ---------------- weight transpose + f32->bf16: w[K][N] -> wt[N][K] --------
__global__ __launch_bounds__(256) void wtrans_kernel(
    const float* __restrict__ w, ushort* __restrict__ wt, int K, int N)
{
    int idx = blockIdx.x * 256 + threadIdx.x;
    if (idx >= K * N) return;
    int n = idx / K, k = idx - n * K;
    wt[idx] = f2bf(w[(size_t)k * N + n]);
}

// ---------------- CPE: depthwise 3x3 + bias + residual ----------------
__global__ __launch_bounds__(256) void cpe_kernel(
    const float* __restrict__ x, const float* __restrict__ w,
    const float* __restrict__ bias, float* __restrict__ out)
{
    const int c = threadIdx.x;
    const int n = blockIdx.x % NN;
    const int b = blockIdx.x / NN;
    const int y = n / WW, xx = n % WW;
    const float* xb = x + (size_t)b * NN * CC;
    float acc = bias[c] + xb[(size_t)n * CC + c];
    #pragma unroll
    for (int dy = -1; dy <= 1; ++dy) {
        int yy = y + dy; if (yy < 0 || yy >= HH) continue;
        #pragma unroll
        for (int dx = -1; dx <= 1; ++dx) {
            int x2 = xx + dx; if (x2 < 0 || x2 >= WW) continue;
            acc += w[c * 9 + (dy + 1) * 3 + (dx + 1)] *
                   xb[(size_t)(yy * WW + x2) * CC + c];
        }
    }
    out[((size_t)b * NN + n) * CC + c] = acc;
}

// ---------------- LayerNorm over C=256, wave-per-row, bf16 out ----------------
__global__ __launch_bounds__(256) void ln_kernel(
    const float* __restrict__ src, const float* __restrict__ g_all,
    const float* __restrict__ b_all, const int* __restrict__ dptr,
    ushort* __restrict__ dst)
{
    const int wid = threadIdx.x >> 6, lane = threadIdx.x & 63;
    const int row = blockIdx.x * 4 + wid;
    const int d = *dptr;
    const float* g = g_all + d * CC;
    const float* be = b_all + d * CC;
    const float* p = src + (size_t)row * CC;
    float4 v = *(const float4*)(p + lane * 4);
    float s = v.x + v.y + v.z + v.w;
    float sq = v.x*v.x + v.y*v.y + v.z*v.z + v.w*v.w;
    #pragma unroll
    for (int off = 1; off < 64; off <<= 1) {
        s  += __shfl_xor(s, off);
        sq += __shfl_xor(sq, off);
    }
    const float mean = s * (1.f / CC);
    const float var = sq * (1.f / CC) - mean * mean;
    const float rs = rsqrtf(var + 1e-5f);
    float4 g4 = *(const float4*)(g + lane * 4);
    float4 b4 = *(const float4*)(be + lane * 4);
    ushort4 o4;
    o4.x = f2bf((v.x - mean) * rs * g4.x + b4.x);
    o4.y = f2bf((v.y - mean) * rs * g4.y + b4.y);
    o4.z = f2bf((v.z - mean) * rs * g4.z + b4.z);
    o4.w = f2bf((v.w - mean) * rs * g4.w + b4.w);
    *(ushort4*)(dst + (size_t)row * CC + lane * 4) = o4;
}

// ---------------- bf16 MFMA GEMM: C = A[M][K] @ Bt[N][K]^T ----------------
// 128x128 tile, BK=32, 4 waves (2x2), each wave 64x64 via 4x4 frags of 16x16x32.
// EPI: 0 = none (f32 out), 2 = bias+gelu (bf16 out), 3 = bias+residual (f32 out)
template<int EPI>
__global__ __launch_bounds__(256) void gemm_mfma(
    const ushort* __restrict__ A, const ushort* __restrict__ Bt,
    const float* __restrict__ bias, const float* __restrict__ res,
    void* __restrict__ Cv, int M, int N, int K)
{
    __shared__ __align__(16) ushort Als[128 * 32];
    __shared__ __align__(16) ushort Bls[128 * 32];
    const int t = threadIdx.x;
    const int bm = blockIdx.y, bn = blockIdx.x;
    const int brow = bm * 128, bcol = bn * 128;
    const int lane = t & 63, w = t >> 6;
    const int wr = w >> 1, wc = w & 1;
    const int lrow = lane & 15, lko = (lane >> 4) * 8;

    const ushort* gA0 = A + (size_t)(brow + (t >> 2)) * K + (t & 3) * 8;
    const ushort* gA1 = gA0 + (size_t)64 * K;
    const ushort* gB0 = Bt + (size_t)(bcol + (t >> 2)) * K + (t & 3) * 8;
    const ushort* gB1 = gB0 + (size_t)64 * K;
    ushort* lA0 = &Als[t * 8];  ushort* lA1 = &Als[64 * 32 + t * 8];
    ushort* lB0 = &Bls[t * 8];  ushort* lB1 = &Bls[64 * 32 + t * 8];

    f32x4 acc[4][4] = {};

    for (int kt = 0; kt < K; kt += 32) {
        gload16(gA0 + kt, lA0);
        gload16(gA1 + kt, lA1);
        gload16(gB0 + kt, lB0);
        gload16(gB1 + kt, lB1);
        __syncthreads();   // drains vmcnt then barrier: LDS tile ready
        bf16x8 af[4], bfr[4];
        #pragma unroll
        for (int i = 0; i < 4; ++i)
            af[i] = *(const bf16x8*)&Als[(wr * 64 + i * 16 + lrow) * 32 + lko];
        #pragma unroll
        for (int j = 0; j < 4; ++j)
            bfr[j] = *(const bf16x8*)&Bls[(wc * 64 + j * 16 + lrow) * 32 + lko];
        #pragma unroll
        for (int i = 0; i < 4; ++i)
            #pragma unroll
            for (int j = 0; j < 4; ++j)
                acc[i][j] = __builtin_amdgcn_mfma_f32_16x16x32_bf16(
                    af[i], bfr[j], acc[i][j], 0, 0, 0);
        __syncthreads();   // all reads done before next overwrite
    }

    float* Cf = (float*)Cv;
    ushort* Ch = (ushort*)Cv;
    #pragma unroll
    for (int j = 0; j < 4; ++j) {
        const int col = bcol + wc * 64 + j * 16 + lrow;
        const float bv = (EPI >= 2) ? bias[col] : 0.f;
        #pragma unroll
        for (int i = 0; i < 4; ++i) {
            const int row0 = brow + wr * 64 + i * 16 + (lane >> 4) * 4;
            #pragma unroll
            for (int r = 0; r < 4; ++r) {
                float v = acc[i][j][r] + bv;
                size_t off = (size_t)(row0 + r) * N + col;
                if (EPI == 2) {
                    v = 0.5f * v * (1.f + erff(v * 0.70710678118654752f));
                    Ch[off] = f2bf(v);
                } else if (EPI == 3) {
                    Cf[off] = v + res[off];
                } else {
                    Cf[off] = v;
                }
            }
        }
    }
}

// ---------------- k-softmax over tokens + kv = k_sm^T @ v ----------------
__global__ __launch_bounds__(256) void kv_kernel(
    const float* __restrict__ qkv, float* __restrict__ kv)
{
    const int bh = blockIdx.x;
    const int b = bh >> 3, h = bh & 7;
    const int t = threadIdx.x;
    const int ck = t & 31, g = t >> 5;
    __shared__ float red[256];
    __shared__ float colmax[32];
    const float* kbase = qkv + (size_t)b * NN * 768 + 256 + h * 32;
    const float* vbase = qkv + (size_t)b * NN * 768 + 512 + h * 32;
    float m = -3.4e38f;
    for (int n = g; n < NN; n += 8) m = fmaxf(m, kbase[(size_t)n * 768 + ck]);
    red[t] = m;
    __syncthreads();
    if (t < 32) {
        float mm = red[t];
        #pragma unroll
        for (int i = 1; i < 8; ++i) mm = fmaxf(mm, red[i * 32 + t]);
        colmax[t] = mm;
    }
    __syncthreads();
    const float cmax = colmax[ck];
    float acc0 = 0.f, acc1 = 0.f, acc2 = 0.f, acc3 = 0.f, csum = 0.f;
    for (int n = 0; n < NN; ++n) {
        float e = __expf(kbase[(size_t)n * 768 + ck] - cmax);
        float4 v4 = *(const float4*)(vbase + (size_t)n * 768 + g * 4);
        acc0 += e * v4.x; acc1 += e * v4.y; acc2 += e * v4.z; acc3 += e * v4.w;
        csum += e;
    }
    const float inv = 1.f / csum;
    float4 o = {acc0 * inv, acc1 * inv, acc2 * inv, acc3 * inv};
    *(float4*)(kv + ((size_t)bh * 32 + ck) * 32 + g * 4) = o;
}

// ---------------- domain gating ----------------
__global__ __launch_bounds__(256) void da_kernel(
    const float* __restrict__ dl, const float* __restrict__ w1,
    const float* __restrict__ b1, const float* __restrict__ w2,
    const float* __restrict__ b2, float* __restrict__ da)
{
    const int b = blockIdx.x, t = threadIdx.x;
    __shared__ float r[HID];
    __shared__ float raw[CC];
    if (t < HID) {
        float s = b1[t];
        #pragma unroll
        for (int k = 0; k < 4; ++k) s += dl[b * 4 + k] * w1[k * HID + t];
        r[t] = fmaxf(s, 0.f);
    }
    __syncthreads();
    float s = b2[t];
    for (int j = 0; j < HID; ++j) s += r[j] * w2[j * CC + t];
    raw[t] = s;
    __syncthreads();
    const int ch = t & 31;
    float m = -3.4e38f;
    #pragma unroll
    for (int hh = 0; hh < NH; ++hh) m = fmaxf(m, raw[hh * 32 + ch]);
    float ssum = 0.f;
    #pragma unroll
    for (int hh = 0; hh < NH; ++hh) ssum += __expf(raw[hh * 32 + ch] - m);
    da[b * CC + t] = __expf(raw[t] - m) / ssum;
}

// ---------------- combine: factor_att + CRPE conv + gating (bf16 out) ------
__global__ __launch_bounds__(256) void combine_kernel(
    const float* __restrict__ qkv, const float* __restrict__ kv,
    const float* __restrict__ da,
    const float* __restrict__ w3, const float* __restrict__ b3,
    const float* __restrict__ w5, const float* __restrict__ b5,
    const float* __restrict__ w7, const float* __restrict__ b7,
    ushort* __restrict__ out)
{
    const int c = threadIdx.x;
    const int n = blockIdx.x % NN, b = blockIdx.x / NN;
    const int y = n / WW, xx = n % WW;
    const int h = c >> 5, ch = c & 31;
    __shared__ float qrow[CC];
    const float* qkvrow = qkv + ((size_t)b * NN + n) * 768;
    qrow[c] = qkvrow[c];
    __syncthreads();
    const float* kvp = kv + (size_t)(b * NH + h) * 32 * 32 + ch;
    float fa = 0.f;
    #pragma unroll
    for (int ck = 0; ck < 32; ++ck) fa += qrow[h * 32 + ck] * kvp[ck * 32];
    int ks; const float* w; float cb;
    if (h < 2)      { ks = 3; w = w3 + c * 9;          cb = b3[c]; }
    else if (h < 5) { ks = 5; w = w5 + (c - 64) * 25;  cb = b5[c - 64]; }
    else            { ks = 7; w = w7 + (c - 160) * 49; cb = b7[c - 160]; }
    const int r = ks >> 1;
    float conv = cb;
    const float* vb = qkv + (size_t)b * NN * 768 + 512 + c;
    for (int dy = -r; dy <= r; ++dy) {
        int yy = y + dy; if (yy < 0 || yy >= HH) continue;
        for (int dx = -r; dx <= r; ++dx) {
            int x2 = xx + dx; if (x2 < 0 || x2 >= WW) continue;
            conv += w[(dy + r) * ks + (dx + r)] * vb[(size_t)(yy * WW + x2) * 768];
        }
    }
    const float qc = qrow[c];
    out[((size_t)b * NN + n) * CC + c] =
        f2bf(da[b * CC + c] * (SCALE * fa + qc * conv));
}

// ---------------- launch ----------------
extern "C" void kernel_launch(void* const* d_in, const int* in_sizes, int n_in,
                              void* d_out, int out_size, void* d_ws, size_t ws_size,
                              hipStream_t stream)
{
    const float* x       = (const float*)d_in[0];
    const float* dlab    = (const float*)d_in[1];
    const float* cpe_w   = (const float*)d_in[2];
    const float* cpe_b   = (const float*)d_in[3];
    const float* ln1_g   = (const float*)d_in[4];
    const float* ln1_b   = (const float*)d_in[5];
    const float* qkv_w   = (const float*)d_in[6];
    const float* proj_w  = (const float*)d_in[7];
    const float* proj_b  = (const float*)d_in[8];
    const float* dl_w1   = (const float*)d_in[9];
    const float* dl_b1   = (const float*)d_in[10];
    const float* dl_w2   = (const float*)d_in[11];
    const float* dl_b2   = (const float*)d_in[12];
    const float* crpe_w3 = (const float*)d_in[13];
    const float* crpe_b3 = (const float*)d_in[14];
    const float* crpe_w5 = (const float*)d_in[15];
    const float* crpe_b5 = (const float*)d_in[16];
    const float* crpe_w7 = (const float*)d_in[17];
    const float* crpe_b7 = (const float*)d_in[18];
    const float* ln2_g   = (const float*)d_in[19];
    const float* ln2_b   = (const float*)d_in[20];
    const float* fc1_w   = (const float*)d_in[21];
    const float* fc1_b   = (const float*)d_in[22];
    const float* fc2_w   = (const float*)d_in[23];
    const float* fc2_b   = (const float*)d_in[24];
    const int*   dptr    = (const int*)d_in[27];

    float* out = (float*)d_out;
    char* W = (char*)d_ws;
    size_t off = 0;
    float* x1 = (float*)(W + off);          off += (size_t)NT * CC * 4;   // f32 [NT,C]
    float* qkv = (float*)(W + off);                                        // f32 [NT,768]
    ushort* hidden = (ushort*)qkv;                                         // overlay: bf16 [NT,1024]
    off += (size_t)NT * 768 * 4;
    ushort* actbf = (ushort*)(W + off);     off += (size_t)NT * CC * 2;   // bf16 [NT,C]
    float* kvb = (float*)(W + off);         off += (size_t)BB * NH * 32 * 32 * 4;
    float* dab = (float*)(W + off);         off += (size_t)BB * CC * 4;
    ushort* wq  = (ushort*)(W + off);       off += (size_t)768 * 256 * 2;
    ushort* wp  = (ushort*)(W + off);       off += (size_t)256 * 256 * 2;
    ushort* w1t = (ushort*)(W + off);       off += (size_t)1024 * 256 * 2;
    ushort* w2t = (ushort*)(W + off);       off += (size_t)256 * 1024 * 2;

    // 0. weight transpose+cast (tiny)
    hipLaunchKernelGGL(wtrans_kernel, dim3(768), dim3(256), 0, stream, qkv_w, wq, 256, 768);
    hipLaunchKernelGGL(wtrans_kernel, dim3(256), dim3(256), 0, stream, proj_w, wp, 256, 256);
    hipLaunchKernelGGL(wtrans_kernel, dim3(1024), dim3(256), 0, stream, fc1_w, w1t, 256, 1024);
    hipLaunchKernelGGL(wtrans_kernel, dim3(1024), dim3(256), 0, stream, fc2_w, w2t, 1024, 256);
    // 1. CPE -> x1 (f32)
    hipLaunchKernelGGL(cpe_kernel, dim3(NT), dim3(256), 0, stream, x, cpe_w, cpe_b, x1);
    // 2. domain gating
    hipLaunchKernelGGL(da_kernel, dim3(BB), dim3(256), 0, stream,
                       dlab, dl_w1, dl_b1, dl_w2, dl_b2, dab);
    // 3. LN1 -> actbf (bf16)
    hipLaunchKernelGGL(ln_kernel, dim3(NT / 4), dim3(256), 0, stream,
                       x1, ln1_g, ln1_b, dptr, actbf);
    // 4. qkv GEMM: [NT,256]bf16 @ [768,256]^T -> qkv f32
    hipLaunchKernelGGL(gemm_mfma<0>, dim3(768 / 128, NT / 128), dim3(256), 0, stream,
                       actbf, wq, nullptr, nullptr, (void*)qkv, NT, 768, 256);
    // 5. token-softmax + kv
    hipLaunchKernelGGL(kv_kernel, dim3(BB * NH), dim3(256), 0, stream, qkv, kvb);
    // 6. combine -> actbf (bf16)
    hipLaunchKernelGGL(combine_kernel, dim3(NT), dim3(256), 0, stream,
                       qkv, kvb, dab, crpe_w3, crpe_b3, crpe_w5, crpe_b5,
                       crpe_w7, crpe_b7, actbf);
    // 7. proj GEMM + bias + residual(x1) -> d_out f32
    hipLaunchKernelGGL(gemm_mfma<3>, dim3(256 / 128, NT / 128), dim3(256), 0, stream,
                       actbf, wp, proj_b, x1, (void*)out, NT, 256, 256);
    // 8. LN2 -> actbf (bf16)
    hipLaunchKernelGGL(ln_kernel, dim3(NT / 4), dim3(256), 0, stream,
                       out, ln2_g, ln2_b, dptr, actbf);
    // 9. fc1 + gelu -> hidden (bf16)
    hipLaunchKernelGGL(gemm_mfma<2>, dim3(1024 / 128, NT / 128), dim3(256), 0, stream,
                       actbf, w1t, fc1_b, nullptr, (void*)hidden, NT, 1024, 256);
    // 10. fc2 + bias + residual(d_out) -> d_out f32
    hipLaunchKernelGGL(gemm_mfma<3>, dim3(256 / 128, NT / 128), dim3(256), 0, stream,
                       hidden, w2t, fc2_b, out, (void*)out, NT, 256, 1024);
}

// Round 3
// 508.343 us; speedup vs baseline: 2.9553x; 1.8151x over previous
//
#include <hip/hip_runtime.h>
#include <hip/hip_bf16.h>
#include <math.h>

// Problem constants (fixed by setup_inputs)
#define BB 8
#define HH 56
#define WW 56
#define NN (HH*WW)          // 3136
#define CC 256
#define NH 8
#define NT (BB*NN)          // 25088
#define HID 128
#define MH 1024
#define SCALE 0.17677669529663687f   // 32^-0.5

typedef __attribute__((ext_vector_type(8))) short bf16x8;
typedef __attribute__((ext_vector_type(4))) float f32x4;

__device__ __forceinline__ ushort f2bf(float f) {
    __hip_bfloat16 h = __float2bfloat16(f);
    return *(ushort*)&h;
}
__device__ __forceinline__ float bf2f(ushort u) {
    union { unsigned int i; float f; } x; x.i = ((unsigned int)u) << 16; return x.f;
}

__device__ __forceinline__ void gload16(const void* g, void* s) {
    __builtin_amdgcn_global_load_lds(
        (const __attribute__((address_space(1))) void*)g,
        (__attribute__((address_space(3))) void*)s, 16, 0, 0);
}

// ---------------- weight transpose + f32->bf16: w[K][N] -> wt[N][K] --------
__global__ __launch_bounds__(256) void wtrans_kernel(
    const float* __restrict__ w, ushort* __restrict__ wt, int K, int N)
{
    int idx = blockIdx.x * 256 + threadIdx.x;
    if (idx >= K * N) return;
    int n = idx / K, k = idx - n * K;
    wt[idx] = f2bf(w[(size_t)k * N + n]);
}

// ---------------- CPE: depthwise 3x3 + bias + residual (row-tiled) --------
__global__ __launch_bounds__(256) void cpe_kernel(
    const float* __restrict__ x, const float* __restrict__ w,
    const float* __restrict__ bias, float* __restrict__ out)
{
    __shared__ ushort vt[3 * 62 * 64];
    const int qq = blockIdx.x, y = blockIdx.y, b = blockIdx.z;
    const int t = threadIdx.x;
    const int c0 = qq * 64;
    // stage 3 rows x 62 cols x 64 ch (zero-padded) as bf16
    for (int p = t >> 4; p < 3 * 62; p += 16) {
        int r = p / 62, lc = p - r * 62, col = lc - 3;
        int gy = y + r - 1;
        float4 v = {0.f, 0.f, 0.f, 0.f};
        if ((unsigned)gy < 56u && (unsigned)col < 56u)
            v = *(const float4*)(x + ((size_t)b * NN + gy * 56 + col) * CC + c0 + (t & 15) * 4);
        ushort4 hv = {f2bf(v.x), f2bf(v.y), f2bf(v.z), f2bf(v.w)};
        *(ushort4*)(&vt[p * 64 + (t & 15) * 4]) = hv;
    }
    __syncthreads();
    const int cl = t & 63, wv = t >> 6;
    const int c = c0 + cl;
    float wreg[9];
    #pragma unroll
    for (int i = 0; i < 9; ++i) wreg[i] = w[c * 9 + i];
    const float bv = bias[c];
    for (int i = 0; i < 14; ++i) {
        int tx = wv * 14 + i;
        float acc = bv + x[((size_t)b * NN + y * 56 + tx) * CC + c];
        #pragma unroll
        for (int dy = 0; dy < 3; ++dy)
            #pragma unroll
            for (int dx = 0; dx < 3; ++dx)
                acc += wreg[dy * 3 + dx] * bf2f(vt[(dy * 62 + tx + 2 + dx) * 64 + cl]);
        out[((size_t)b * NN + y * 56 + tx) * CC + c] = acc;
    }
}

// ---------------- LayerNorm over C=256, wave-per-row, bf16 out ----------------
__global__ __launch_bounds__(256) void ln_kernel(
    const float* __restrict__ src, const float* __restrict__ g_all,
    const float* __restrict__ b_all, const int* __restrict__ dptr,
    ushort* __restrict__ dst)
{
    const int wid = threadIdx.x >> 6, lane = threadIdx.x & 63;
    const int row = blockIdx.x * 4 + wid;
    const int d = *dptr;
    const float* g = g_all + d * CC;
    const float* be = b_all + d * CC;
    const float* p = src + (size_t)row * CC;
    float4 v = *(const float4*)(p + lane * 4);
    float s = v.x + v.y + v.z + v.w;
    float sq = v.x*v.x + v.y*v.y + v.z*v.z + v.w*v.w;
    #pragma unroll
    for (int off = 1; off < 64; off <<= 1) {
        s  += __shfl_xor(s, off);
        sq += __shfl_xor(sq, off);
    }
    const float mean = s * (1.f / CC);
    const float var = sq * (1.f / CC) - mean * mean;
    const float rs = rsqrtf(var + 1e-5f);
    float4 g4 = *(const float4*)(g + lane * 4);
    float4 b4 = *(const float4*)(be + lane * 4);
    ushort4 o4;
    o4.x = f2bf((v.x - mean) * rs * g4.x + b4.x);
    o4.y = f2bf((v.y - mean) * rs * g4.y + b4.y);
    o4.z = f2bf((v.z - mean) * rs * g4.z + b4.z);
    o4.w = f2bf((v.w - mean) * rs * g4.w + b4.w);
    *(ushort4*)(dst + (size_t)row * CC + lane * 4) = o4;
}

// ---------------- bf16 MFMA GEMM: C = A[M][K] @ Bt[N][K]^T ----------------
template<int EPI>
__global__ __launch_bounds__(256) void gemm_mfma(
    const ushort* __restrict__ A, const ushort* __restrict__ Bt,
    const float* __restrict__ bias, const float* __restrict__ res,
    void* __restrict__ Cv, int M, int N, int K)
{
    __shared__ __align__(16) ushort Als[128 * 32];
    __shared__ __align__(16) ushort Bls[128 * 32];
    const int t = threadIdx.x;
    const int bm = blockIdx.y, bn = blockIdx.x;
    const int brow = bm * 128, bcol = bn * 128;
    const int lane = t & 63, w = t >> 6;
    const int wr = w >> 1, wc = w & 1;
    const int lrow = lane & 15, lko = (lane >> 4) * 8;

    const ushort* gA0 = A + (size_t)(brow + (t >> 2)) * K + (t & 3) * 8;
    const ushort* gA1 = gA0 + (size_t)64 * K;
    const ushort* gB0 = Bt + (size_t)(bcol + (t >> 2)) * K + (t & 3) * 8;
    const ushort* gB1 = gB0 + (size_t)64 * K;
    ushort* lA0 = &Als[t * 8];  ushort* lA1 = &Als[64 * 32 + t * 8];
    ushort* lB0 = &Bls[t * 8];  ushort* lB1 = &Bls[64 * 32 + t * 8];

    f32x4 acc[4][4] = {};

    for (int kt = 0; kt < K; kt += 32) {
        gload16(gA0 + kt, lA0);
        gload16(gA1 + kt, lA1);
        gload16(gB0 + kt, lB0);
        gload16(gB1 + kt, lB1);
        __syncthreads();
        bf16x8 af[4], bfr[4];
        #pragma unroll
        for (int i = 0; i < 4; ++i)
            af[i] = *(const bf16x8*)&Als[(wr * 64 + i * 16 + lrow) * 32 + lko];
        #pragma unroll
        for (int j = 0; j < 4; ++j)
            bfr[j] = *(const bf16x8*)&Bls[(wc * 64 + j * 16 + lrow) * 32 + lko];
        #pragma unroll
        for (int i = 0; i < 4; ++i)
            #pragma unroll
            for (int j = 0; j < 4; ++j)
                acc[i][j] = __builtin_amdgcn_mfma_f32_16x16x32_bf16(
                    af[i], bfr[j], acc[i][j], 0, 0, 0);
        __syncthreads();
    }

    float* Cf = (float*)Cv;
    ushort* Ch = (ushort*)Cv;
    #pragma unroll
    for (int j = 0; j < 4; ++j) {
        const int col = bcol + wc * 64 + j * 16 + lrow;
        const float bv = (EPI >= 2) ? bias[col] : 0.f;
        #pragma unroll
        for (int i = 0; i < 4; ++i) {
            const int row0 = brow + wr * 64 + i * 16 + (lane >> 4) * 4;
            #pragma unroll
            for (int r = 0; r < 4; ++r) {
                float v = acc[i][j][r] + bv;
                size_t off = (size_t)(row0 + r) * N + col;
                if (EPI == 2) {
                    v = 0.5f * v * (1.f + erff(v * 0.70710678118654752f));
                    Ch[off] = f2bf(v);
                } else if (EPI == 3) {
                    Cf[off] = v + res[off];
                } else {
                    Cf[off] = v;
                }
            }
        }
    }
}

// ---------------- k softmax: pass 1, per-chunk column max ----------------
__global__ __launch_bounds__(256) void kmax1_kernel(
    const float* __restrict__ qkv, float* __restrict__ pmax)
{
    const int chunk = blockIdx.x, b = blockIdx.y, c = threadIdx.x;
    const float* kb = qkv + (size_t)(b * NN + chunk * 98) * 768 + 256 + c;
    float m = -3.4e38f;
    for (int i = 0; i < 98; ++i) m = fmaxf(m, kb[(size_t)i * 768]);
    pmax[(b * 32 + chunk) * CC + c] = m;
}

__global__ __launch_bounds__(256) void kmax2_kernel(
    const float* __restrict__ pmax, float* __restrict__ cmax)
{
    const int b = blockIdx.x, c = threadIdx.x;
    float m = -3.4e38f;
    #pragma unroll
    for (int i = 0; i < 32; ++i) m = fmaxf(m, pmax[(b * 32 + i) * CC + c]);
    cmax[b * CC + c] = m;
}

// ---------------- kv partial: per-chunk exp-weighted sums ----------------
__global__ __launch_bounds__(256) void kvacc_kernel(
    const float* __restrict__ qkv, const float* __restrict__ cmax,
    float* __restrict__ partial, float* __restrict__ psum)
{
    const int chunk = blockIdx.x, h = blockIdx.y, b = blockIdx.z;
    const int t = threadIdx.x;
    const int ck = t & 31, g = t >> 5;
    const int n0 = chunk * 196;
    const float* kb = qkv + (size_t)(b * NN + n0) * 768 + 256 + h * 32 + ck;
    const float* vb = qkv + (size_t)(b * NN + n0) * 768 + 512 + h * 32 + g * 4;
    const float cm = cmax[b * CC + h * 32 + ck];
    float a0 = 0.f, a1 = 0.f, a2 = 0.f, a3 = 0.f, s = 0.f;
    for (int i = 0; i < 196; ++i) {
        float e = __expf(kb[(size_t)i * 768] - cm);
        float4 v4 = *(const float4*)(vb + (size_t)i * 768);
        a0 += e * v4.x; a1 += e * v4.y; a2 += e * v4.z; a3 += e * v4.w;
        s += e;
    }
    float4 o = {a0, a1, a2, a3};
    *(float4*)(partial + ((((size_t)chunk * 8 + b) * 8 + h) * 32 + ck) * 32 + g * 4) = o;
    if (g == 0) psum[((chunk * 8 + b) * 8 + h) * 32 + ck] = s;
}

__global__ __launch_bounds__(256) void kvnorm_kernel(
    const float* __restrict__ partial, const float* __restrict__ psum,
    float* __restrict__ kv)
{
    const int idx = blockIdx.x * 256 + threadIdx.x;   // [b][h][ck][cv]
    const int base = idx;                              // within one chunk block
    const int ckidx = idx >> 5;                        // [b][h][ck]
    float sum = 0.f, cs = 0.f;
    #pragma unroll
    for (int ch = 0; ch < 16; ++ch) {
        sum += partial[(size_t)ch * 65536 + base];
        cs  += psum[ch * 2048 + ckidx];
    }
    kv[idx] = sum / cs;
}

// ---------------- domain gating ----------------
__global__ __launch_bounds__(256) void da_kernel(
    const float* __restrict__ dl, const float* __restrict__ w1,
    const float* __restrict__ b1, const float* __restrict__ w2,
    const float* __restrict__ b2, float* __restrict__ da)
{
    const int b = blockIdx.x, t = threadIdx.x;
    __shared__ float r[HID];
    __shared__ float raw[CC];
    if (t < HID) {
        float s = b1[t];
        #pragma unroll
        for (int k = 0; k < 4; ++k) s += dl[b * 4 + k] * w1[k * HID + t];
        r[t] = fmaxf(s, 0.f);
    }
    __syncthreads();
    float s = b2[t];
    for (int j = 0; j < HID; ++j) s += r[j] * w2[j * CC + t];
    raw[t] = s;
    __syncthreads();
    const int ch = t & 31;
    float m = -3.4e38f;
    #pragma unroll
    for (int hh = 0; hh < NH; ++hh) m = fmaxf(m, raw[hh * 32 + ch]);
    float ssum = 0.f;
    #pragma unroll
    for (int hh = 0; hh < NH; ++hh) ssum += __expf(raw[hh * 32 + ch] - m);
    da[b * CC + t] = __expf(raw[t] - m) / ssum;
}

// ---------------- combine: factor_att + CRPE conv + gating (row-tiled) -----
template<int KS, int RR>
__device__ __forceinline__ float conv_eval(const ushort* vtile, const float* wreg,
                                           float cbias, int tx, int cl)
{
    float conv = cbias;
    constexpr int r = KS / 2;
    #pragma unroll
    for (int dy = 0; dy < KS; ++dy)
        #pragma unroll
        for (int dx = 0; dx < KS; ++dx)
            conv += wreg[dy * KS + dx] *
                    bf2f(vtile[((RR - r + dy) * 62 + (tx + 3 - r + dx)) * 64 + cl]);
    return conv;
}

template<int KSA, int KSB>
__device__ __forceinline__ void combine_body(
    int qq, const float* __restrict__ qkv, const float* __restrict__ kvn,
    const float* __restrict__ da,
    const float* __restrict__ w3, const float* __restrict__ b3,
    const float* __restrict__ w5, const float* __restrict__ b5,
    const float* __restrict__ w7, const float* __restrict__ b7,
    ushort* __restrict__ out, ushort* vtile, float* qtile, float* kvlds)
{
    constexpr int RR = (KSB / 2);
    const int y = blockIdx.y, b = blockIdx.z;
    const int t = threadIdx.x;
    const int c0 = qq * 64;
    // stage v tile (zero-padded)
    const int NPOS = (2 * RR + 1) * 62;
    for (int p = t >> 4; p < NPOS; p += 16) {
        int r = p / 62, lc = p - r * 62, col = lc - 3;
        int gy = y + r - RR;
        float4 v = {0.f, 0.f, 0.f, 0.f};
        if ((unsigned)gy < 56u && (unsigned)col < 56u)
            v = *(const float4*)(qkv + ((size_t)b * NN + gy * 56 + col) * 768 + 512 + c0 + (t & 15) * 4);
        ushort4 hv = {f2bf(v.x), f2bf(v.y), f2bf(v.z), f2bf(v.w)};
        *(ushort4*)(&vtile[p * 64 + (t & 15) * 4]) = hv;
    }
    // stage q row (f32)
    for (int p = t >> 4; p < 56; p += 16) {
        float4 qa = *(const float4*)(qkv + ((size_t)b * NN + y * 56 + p) * 768 + c0 + (t & 15) * 4);
        *(float4*)(&qtile[p * 64 + (t & 15) * 4]) = qa;
    }
    // stage kv (2 heads)
    const float* kvsrc = kvn + ((size_t)b * NH + 2 * qq) * 1024;
    for (int i = t; i < 2048; i += 256) kvlds[i] = kvsrc[i];
    __syncthreads();

    const int cl = t & 63, wv = t >> 6;
    const int c = c0 + cl;
    float wreg[KSB * KSB];
    const float* wbase; float cbias;
    if (c < 64)       { wbase = w3 + c * 9;          cbias = b3[c]; }
    else if (c < 160) { wbase = w5 + (c - 64) * 25;  cbias = b5[c - 64]; }
    else              { wbase = w7 + (c - 160) * 49; cbias = b7[c - 160]; }
    if (KSA == KSB || cl < 32) {
        #pragma unroll
        for (int i = 0; i < KSA * KSA; ++i) wreg[i] = wbase[i];
    }
    if (KSA != KSB && cl >= 32) {
        #pragma unroll
        for (int i = 0; i < KSB * KSB; ++i) wreg[i] = wbase[i];
    }
    const float dav = da[b * CC + c];
    const int qb = (cl & 32);
    const int kvbase = (cl >> 5) * 1024 + (cl & 31);

    for (int i = 0; i < 14; ++i) {
        const int tx = wv * 14 + i;
        float fa = 0.f;
        #pragma unroll
        for (int ck = 0; ck < 32; ++ck)
            fa += qtile[tx * 64 + qb + ck] * kvlds[kvbase + ck * 32];
        const float qc = qtile[tx * 64 + cl];
        float conv;
        if constexpr (KSA == KSB) {
            conv = conv_eval<KSA, RR>(vtile, wreg, cbias, tx, cl);
        } else {
            if (cl < 32) conv = conv_eval<KSA, RR>(vtile, wreg, cbias, tx, cl);
            else         conv = conv_eval<KSB, RR>(vtile, wreg, cbias, tx, cl);
        }
        out[((size_t)b * NN + y * 56 + tx) * CC + c] =
            f2bf(dav * (SCALE * fa + qc * conv));
    }
}

__global__ __launch_bounds__(256) void combine_kernel(
    const float* __restrict__ qkv, const float* __restrict__ kvn,
    const float* __restrict__ da,
    const float* __restrict__ w3, const float* __restrict__ b3,
    const float* __restrict__ w5, const float* __restrict__ b5,
    const float* __restrict__ w7, const float* __restrict__ b7,
    ushort* __restrict__ out)
{
    __shared__ ushort vtile[7 * 62 * 64];
    __shared__ float qtile[56 * 64];
    __shared__ float kvlds[2048];
    switch (blockIdx.x) {
    case 0: combine_body<3,3>(0, qkv, kvn, da, w3,b3,w5,b5,w7,b7, out, vtile, qtile, kvlds); break;
    case 1: combine_body<5,5>(1, qkv, kvn, da, w3,b3,w5,b5,w7,b7, out, vtile, qtile, kvlds); break;
    case 2: combine_body<5,7>(2, qkv, kvn, da, w3,b3,w5,b5,w7,b7, out, vtile, qtile, kvlds); break;
    default: combine_body<7,7>(3, qkv, kvn, da, w3,b3,w5,b5,w7,b7, out, vtile, qtile, kvlds); break;
    }
}

// ---------------- launch ----------------
extern "C" void kernel_launch(void* const* d_in, const int* in_sizes, int n_in,
                              void* d_out, int out_size, void* d_ws, size_t ws_size,
                              hipStream_t stream)
{
    const float* x       = (const float*)d_in[0];
    const float* dlab    = (const float*)d_in[1];
    const float* cpe_w   = (const float*)d_in[2];
    const float* cpe_b   = (const float*)d_in[3];
    const float* ln1_g   = (const float*)d_in[4];
    const float* ln1_b   = (const float*)d_in[5];
    const float* qkv_w   = (const float*)d_in[6];
    const float* proj_w  = (const float*)d_in[7];
    const float* proj_b  = (const float*)d_in[8];
    const float* dl_w1   = (const float*)d_in[9];
    const float* dl_b1   = (const float*)d_in[10];
    const float* dl_w2   = (const float*)d_in[11];
    const float* dl_b2   = (const float*)d_in[12];
    const float* crpe_w3 = (const float*)d_in[13];
    const float* crpe_b3 = (const float*)d_in[14];
    const float* crpe_w5 = (const float*)d_in[15];
    const float* crpe_b5 = (const float*)d_in[16];
    const float* crpe_w7 = (const float*)d_in[17];
    const float* crpe_b7 = (const float*)d_in[18];
    const float* ln2_g   = (const float*)d_in[19];
    const float* ln2_b   = (const float*)d_in[20];
    const float* fc1_w   = (const float*)d_in[21];
    const float* fc1_b   = (const float*)d_in[22];
    const float* fc2_w   = (const float*)d_in[23];
    const float* fc2_b   = (const float*)d_in[24];
    const int*   dptr    = (const int*)d_in[27];

    float* out = (float*)d_out;
    char* W = (char*)d_ws;
    size_t off = 0;
    float* x1 = (float*)(W + off);          off += (size_t)NT * CC * 4;   // f32 [NT,C]
    float* qkv = (float*)(W + off);                                        // f32 [NT,768]
    ushort* hidden = (ushort*)qkv;                                         // overlay: bf16 [NT,1024]
    off += (size_t)NT * 768 * 4;
    ushort* actbf = (ushort*)(W + off);     off += (size_t)NT * CC * 2;   // bf16 [NT,C]
    // overlay: kv partials live only between qkv-GEMM and combine, while actbf is dead
    float* partial = (float*)actbf;                    // 16*65536 f32 = 4 MB
    float* psum = partial + (size_t)16 * 65536;        // 32768 f32
    float* kvb = (float*)(W + off);         off += (size_t)65536 * 4;
    float* dab = (float*)(W + off);         off += (size_t)BB * CC * 4;
    float* pmax = (float*)(W + off);        off += (size_t)BB * 32 * CC * 4;
    float* cmax = (float*)(W + off);        off += (size_t)BB * CC * 4;
    ushort* wq  = (ushort*)(W + off);       off += (size_t)768 * 256 * 2;
    ushort* wp  = (ushort*)(W + off);       off += (size_t)256 * 256 * 2;
    ushort* w1t = (ushort*)(W + off);       off += (size_t)1024 * 256 * 2;
    ushort* w2t = (ushort*)(W + off);       off += (size_t)256 * 1024 * 2;

    // 0. weight transpose+cast (tiny)
    hipLaunchKernelGGL(wtrans_kernel, dim3(768), dim3(256), 0, stream, qkv_w, wq, 256, 768);
    hipLaunchKernelGGL(wtrans_kernel, dim3(256), dim3(256), 0, stream, proj_w, wp, 256, 256);
    hipLaunchKernelGGL(wtrans_kernel, dim3(1024), dim3(256), 0, stream, fc1_w, w1t, 256, 1024);
    hipLaunchKernelGGL(wtrans_kernel, dim3(1024), dim3(256), 0, stream, fc2_w, w2t, 1024, 256);
    // 1. CPE -> x1 (f32)
    hipLaunchKernelGGL(cpe_kernel, dim3(4, 56, 8), dim3(256), 0, stream, x, cpe_w, cpe_b, x1);
    // 2. domain gating
    hipLaunchKernelGGL(da_kernel, dim3(BB), dim3(256), 0, stream,
                       dlab, dl_w1, dl_b1, dl_w2, dl_b2, dab);
    // 3. LN1 -> actbf (bf16)
    hipLaunchKernelGGL(ln_kernel, dim3(NT / 4), dim3(256), 0, stream,
                       x1, ln1_g, ln1_b, dptr, actbf);
    // 4. qkv GEMM: [NT,256]bf16 @ [768,256]^T -> qkv f32
    hipLaunchKernelGGL(gemm_mfma<0>, dim3(768 / 128, NT / 128), dim3(256), 0, stream,
                       actbf, wq, nullptr, nullptr, (void*)qkv, NT, 768, 256);
    // 5. k column max (chunked) + reduce
    hipLaunchKernelGGL(kmax1_kernel, dim3(32, 8), dim3(256), 0, stream, qkv, pmax);
    hipLaunchKernelGGL(kmax2_kernel, dim3(8), dim3(256), 0, stream, pmax, cmax);
    // 6. kv partial sums + normalize
    hipLaunchKernelGGL(kvacc_kernel, dim3(16, 8, 8), dim3(256), 0, stream,
                       qkv, cmax, partial, psum);
    hipLaunchKernelGGL(kvnorm_kernel, dim3(256), dim3(256), 0, stream,
                       partial, psum, kvb);
    // 7. combine -> actbf (bf16)
    hipLaunchKernelGGL(combine_kernel, dim3(4, 56, 8), dim3(256), 0, stream,
                       qkv, kvb, dab, crpe_w3, crpe_b3, crpe_w5, crpe_b5,
                       crpe_w7, crpe_b7, actbf);
    // 8. proj GEMM + bias + residual(x1) -> d_out f32
    hipLaunchKernelGGL(gemm_mfma<3>, dim3(256 / 128, NT / 128), dim3(256), 0, stream,
                       actbf, wp, proj_b, x1, (void*)out, NT, 256, 256);
    // 9. LN2 -> actbf (bf16)
    hipLaunchKernelGGL(ln_kernel, dim3(NT / 4), dim3(256), 0, stream,
                       out, ln2_g, ln2_b, dptr, actbf);
    // 10. fc1 + gelu -> hidden (bf16)
    hipLaunchKernelGGL(gemm_mfma<2>, dim3(1024 / 128, NT / 128), dim3(256), 0, stream,
                       actbf, w1t, fc1_b, nullptr, (void*)hidden, NT, 1024, 256);
    // 11. fc2 + bias + residual(d_out) -> d_out f32
    hipLaunchKernelGGL(gemm_mfma<3>, dim3(256 / 128, NT / 128), dim3(256), 0, stream,
                       hidden, w2t, fc2_b, out, (void*)out, NT, 256, 1024);
}

// Round 4
// 437.428 us; speedup vs baseline: 3.4345x; 1.1621x over previous
//
#include <hip/hip_runtime.h>
#include <hip/hip_bf16.h>
#include <math.h>

// Problem constants (fixed by setup_inputs)
#define BB 8
#define HH 56
#define WW 56
#define NN (HH*WW)          // 3136
#define CC 256
#define NH 8
#define NT (BB*NN)          // 25088
#define HID 128
#define MH 1024
#define SCALE 0.17677669529663687f   // 32^-0.5

typedef __attribute__((ext_vector_type(8))) short bf16x8;
typedef __attribute__((ext_vector_type(4))) float f32x4;

__device__ __forceinline__ ushort f2bf(float f) {
    __hip_bfloat16 h = __float2bfloat16(f);
    return *(ushort*)&h;
}
__device__ __forceinline__ uint pk2(float lo, float hi) {
    return ((uint)f2bf(hi) << 16) | (uint)f2bf(lo);
}
__device__ __forceinline__ float unlo(uint u) { return __uint_as_float(u << 16); }
__device__ __forceinline__ float unhi(uint u) { return __uint_as_float(u & 0xFFFF0000u); }

__device__ __forceinline__ void gload16(const void* g, void* s) {
    __builtin_amdgcn_global_load_lds(
        (const __attribute__((address_space(1))) void*)g,
        (__attribute__((address_space(3))) void*)s, 16, 0, 0);
}

// ---------------- weight transpose + f32->bf16: w[K][N] -> wt[N][K] --------
__global__ __launch_bounds__(256) void wtrans_kernel(
    const float* __restrict__ w, ushort* __restrict__ wt, int K, int N)
{
    int idx = blockIdx.x * 256 + threadIdx.x;
    if (idx >= K * N) return;
    int n = idx / K, k = idx - n * K;
    wt[idx] = f2bf(w[(size_t)k * N + n]);
}

// ---------------- CPE: depthwise 3x3 + bias + residual (paired channels) ----
__global__ __launch_bounds__(256) void cpe_kernel(
    const float* __restrict__ x, const float* __restrict__ w,
    const float* __restrict__ bias, float* __restrict__ out)
{
    __shared__ uint vt[3 * 34 * 32];
    const int qq = blockIdx.x >> 1, hx = blockIdx.x & 1;
    const int y = blockIdx.y, b = blockIdx.z;
    const int c0 = qq * 64, x0 = hx * 28;
    const int t = threadIdx.x;
    const int p = t & 31;
    // stage 3 rows x 34 cols, bf16 channel pairs (c0+p, c0+32+p)
    for (int rr = 0; rr < 3; ++rr) {
        int gy = y + rr - 1;
        const float* src = x + ((size_t)b * NN + gy * 56) * CC + c0;
        for (int lc = t >> 5; lc < 34; lc += 8) {
            int gx = x0 + lc - 3;
            float vlo = 0.f, vhi = 0.f;
            if ((unsigned)gy < 56u && (unsigned)gx < 56u) {
                vlo = src[(size_t)gx * CC + p];
                vhi = src[(size_t)gx * CC + p + 32];
            }
            vt[(rr * 34 + lc) * 32 + p] = pk2(vlo, vhi);
        }
    }
    uint wp[9];
    {
        const float* wl = w + (c0 + p) * 9;
        const float* wh = w + (c0 + 32 + p) * 9;
        #pragma unroll
        for (int i = 0; i < 9; ++i) wp[i] = pk2(wl[i], wh[i]);
    }
    const float blo = bias[c0 + p], bhi = bias[c0 + 32 + p];
    __syncthreads();

    const int wv = t >> 6, th = (t >> 5) & 1;
    int txl[4]; float clo[4], chi[4];
    #pragma unroll
    for (int jj = 0; jj < 4; ++jj) {
        int j = wv + jj * 4; if (j > 13) j = 13;
        txl[jj] = 2 * j + th;
        clo[jj] = blo; chi[jj] = bhi;
    }
    #pragma unroll
    for (int dy = 0; dy < 3; ++dy)
        #pragma unroll
        for (int dx = 0; dx < 3; ++dx) {
            const uint wpk = wp[dy * 3 + dx];
            const float wl = unlo(wpk), wh = unhi(wpk);
            #pragma unroll
            for (int jj = 0; jj < 4; ++jj) {
                uint vv = vt[(dy * 34 + txl[jj] + 2 + dx) * 32 + p];
                clo[jj] = fmaf(unlo(vv), wl, clo[jj]);
                chi[jj] = fmaf(unhi(vv), wh, chi[jj]);
            }
        }
    #pragma unroll
    for (int jj = 0; jj < 4; ++jj) {
        size_t tokg = (size_t)b * NN + y * 56 + x0 + txl[jj];
        const float* row = x + tokg * CC;
        out[tokg * CC + c0 + p]      = clo[jj] + row[c0 + p];
        out[tokg * CC + c0 + 32 + p] = chi[jj] + row[c0 + 32 + p];
    }
}

// ---------------- LayerNorm over C=256, wave-per-row, bf16 out ----------------
__global__ __launch_bounds__(256) void ln_kernel(
    const float* __restrict__ src, const float* __restrict__ g_all,
    const float* __restrict__ b_all, const int* __restrict__ dptr,
    ushort* __restrict__ dst)
{
    const int wid = threadIdx.x >> 6, lane = threadIdx.x & 63;
    const int row = blockIdx.x * 4 + wid;
    const int d = *dptr;
    const float* g = g_all + d * CC;
    const float* be = b_all + d * CC;
    const float* p = src + (size_t)row * CC;
    float4 v = *(const float4*)(p + lane * 4);
    float s = v.x + v.y + v.z + v.w;
    float sq = v.x*v.x + v.y*v.y + v.z*v.z + v.w*v.w;
    #pragma unroll
    for (int off = 1; off < 64; off <<= 1) {
        s  += __shfl_xor(s, off);
        sq += __shfl_xor(sq, off);
    }
    const float mean = s * (1.f / CC);
    const float var = sq * (1.f / CC) - mean * mean;
    const float rs = rsqrtf(var + 1e-5f);
    float4 g4 = *(const float4*)(g + lane * 4);
    float4 b4 = *(const float4*)(be + lane * 4);
    ushort4 o4;
    o4.x = f2bf((v.x - mean) * rs * g4.x + b4.x);
    o4.y = f2bf((v.y - mean) * rs * g4.y + b4.y);
    o4.z = f2bf((v.z - mean) * rs * g4.z + b4.z);
    o4.w = f2bf((v.w - mean) * rs * g4.w + b4.w);
    *(ushort4*)(dst + (size_t)row * CC + lane * 4) = o4;
}

// ---------------- bf16 MFMA GEMM: C = A[M][K] @ Bt[N][K]^T ----------------
template<int EPI>
__global__ __launch_bounds__(256) void gemm_mfma(
    const ushort* __restrict__ A, const ushort* __restrict__ Bt,
    const float* __restrict__ bias, const float* __restrict__ res,
    void* __restrict__ Cv, int M, int N, int K)
{
    __shared__ __align__(16) ushort Als[128 * 32];
    __shared__ __align__(16) ushort Bls[128 * 32];
    const int t = threadIdx.x;
    const int bm = blockIdx.y, bn = blockIdx.x;
    const int brow = bm * 128, bcol = bn * 128;
    const int lane = t & 63, w = t >> 6;
    const int wr = w >> 1, wc = w & 1;
    const int lrow = lane & 15, lko = (lane >> 4) * 8;

    const ushort* gA0 = A + (size_t)(brow + (t >> 2)) * K + (t & 3) * 8;
    const ushort* gA1 = gA0 + (size_t)64 * K;
    const ushort* gB0 = Bt + (size_t)(bcol + (t >> 2)) * K + (t & 3) * 8;
    const ushort* gB1 = gB0 + (size_t)64 * K;
    ushort* lA0 = &Als[t * 8];  ushort* lA1 = &Als[64 * 32 + t * 8];
    ushort* lB0 = &Bls[t * 8];  ushort* lB1 = &Bls[64 * 32 + t * 8];

    f32x4 acc[4][4] = {};

    for (int kt = 0; kt < K; kt += 32) {
        gload16(gA0 + kt, lA0);
        gload16(gA1 + kt, lA1);
        gload16(gB0 + kt, lB0);
        gload16(gB1 + kt, lB1);
        __syncthreads();
        bf16x8 af[4], bfr[4];
        #pragma unroll
        for (int i = 0; i < 4; ++i)
            af[i] = *(const bf16x8*)&Als[(wr * 64 + i * 16 + lrow) * 32 + lko];
        #pragma unroll
        for (int j = 0; j < 4; ++j)
            bfr[j] = *(const bf16x8*)&Bls[(wc * 64 + j * 16 + lrow) * 32 + lko];
        #pragma unroll
        for (int i = 0; i < 4; ++i)
            #pragma unroll
            for (int j = 0; j < 4; ++j)
                acc[i][j] = __builtin_amdgcn_mfma_f32_16x16x32_bf16(
                    af[i], bfr[j], acc[i][j], 0, 0, 0);
        __syncthreads();
    }

    float* Cf = (float*)Cv;
    ushort* Ch = (ushort*)Cv;
    #pragma unroll
    for (int j = 0; j < 4; ++j) {
        const int col = bcol + wc * 64 + j * 16 + lrow;
        const float bv = (EPI >= 2) ? bias[col] : 0.f;
        #pragma unroll
        for (int i = 0; i < 4; ++i) {
            const int row0 = brow + wr * 64 + i * 16 + (lane >> 4) * 4;
            #pragma unroll
            for (int r = 0; r < 4; ++r) {
                float v = acc[i][j][r] + bv;
                size_t off = (size_t)(row0 + r) * N + col;
                if (EPI == 2) {
                    v = 0.5f * v * (1.f + erff(v * 0.70710678118654752f));
                    Ch[off] = f2bf(v);
                } else if (EPI == 3) {
                    Cf[off] = v + res[off];
                } else {
                    Cf[off] = v;
                }
            }
        }
    }
}

// ---------------- k softmax: per-chunk column max + reduce ----------------
__global__ __launch_bounds__(256) void kmax1_kernel(
    const float* __restrict__ qkv, float* __restrict__ pmax)
{
    const int chunk = blockIdx.x, b = blockIdx.y, c = threadIdx.x;
    const float* kb = qkv + (size_t)(b * NN + chunk * 98) * 768 + 256 + c;
    float m = -3.4e38f;
    for (int i = 0; i < 98; ++i) m = fmaxf(m, kb[(size_t)i * 768]);
    pmax[(b * 32 + chunk) * CC + c] = m;
}

__global__ __launch_bounds__(256) void kmax2_kernel(
    const float* __restrict__ pmax, float* __restrict__ cmax)
{
    const int b = blockIdx.x, c = threadIdx.x;
    float m = -3.4e38f;
    #pragma unroll
    for (int i = 0; i < 32; ++i) m = fmaxf(m, pmax[(b * 32 + i) * CC + c]);
    cmax[b * CC + c] = m;
}

// ---------------- kv partial: per-chunk exp-weighted sums ----------------
__global__ __launch_bounds__(256) void kvacc_kernel(
    const float* __restrict__ qkv, const float* __restrict__ cmax,
    float* __restrict__ partial, float* __restrict__ psum)
{
    const int chunk = blockIdx.x, h = blockIdx.y, b = blockIdx.z;
    const int t = threadIdx.x;
    const int ck = t & 31, g = t >> 5;
    const int n0 = chunk * 196;
    const float* kb = qkv + (size_t)(b * NN + n0) * 768 + 256 + h * 32 + ck;
    const float* vb = qkv + (size_t)(b * NN + n0) * 768 + 512 + h * 32 + g * 4;
    const float cm = cmax[b * CC + h * 32 + ck];
    float a0 = 0.f, a1 = 0.f, a2 = 0.f, a3 = 0.f, s = 0.f;
    for (int i = 0; i < 196; ++i) {
        float e = __expf(kb[(size_t)i * 768] - cm);
        float4 v4 = *(const float4*)(vb + (size_t)i * 768);
        a0 += e * v4.x; a1 += e * v4.y; a2 += e * v4.z; a3 += e * v4.w;
        s += e;
    }
    float4 o = {a0, a1, a2, a3};
    *(float4*)(partial + ((((size_t)chunk * 8 + b) * 8 + h) * 32 + ck) * 32 + g * 4) = o;
    if (g == 0) psum[((chunk * 8 + b) * 8 + h) * 32 + ck] = s;
}

__global__ __launch_bounds__(256) void kvnorm_kernel(
    const float* __restrict__ partial, const float* __restrict__ psum,
    float* __restrict__ kv)
{
    const int idx = blockIdx.x * 256 + threadIdx.x;   // [b][h][ck][cv]
    const int ckidx = idx >> 5;
    float sum = 0.f, cs = 0.f;
    #pragma unroll
    for (int ch = 0; ch < 16; ++ch) {
        sum += partial[(size_t)ch * 65536 + idx];
        cs  += psum[ch * 2048 + ckidx];
    }
    kv[idx] = sum / cs;
}

// ---------------- fa GEMM: fa[b,h] = q[b,:,h] @ kv[b,h]  (into k-slot) ------
__global__ __launch_bounds__(256) void fa_kernel(
    float* __restrict__ qkv, const float* __restrict__ kvb)
{
    const int mt = blockIdx.x, h = blockIdx.y, b = blockIdx.z;
    const int t = threadIdx.x;
    const int lane = t & 63, wv = t >> 6;
    const int row0 = mt * 448 + wv * 112;
    const int lr = lane & 15, lk = (lane >> 4) * 8;

    bf16x8 bfr[2];
    #pragma unroll
    for (int jj = 0; jj < 2; ++jj)
        #pragma unroll
        for (int e = 0; e < 8; ++e)
            bfr[jj][e] = (short)f2bf(kvb[((size_t)(b * 8 + h) * 32 + lk + e) * 32 + jj * 16 + lr]);

    #pragma unroll
    for (int i = 0; i < 7; ++i) {
        size_t tok = (size_t)b * NN + row0 + i * 16 + lr;
        const float* qp = qkv + tok * 768 + h * 32 + lk;
        float4 qa = *(const float4*)qp;
        float4 qb2 = *(const float4*)(qp + 4);
        bf16x8 af;
        af[0] = (short)f2bf(qa.x);  af[1] = (short)f2bf(qa.y);
        af[2] = (short)f2bf(qa.z);  af[3] = (short)f2bf(qa.w);
        af[4] = (short)f2bf(qb2.x); af[5] = (short)f2bf(qb2.y);
        af[6] = (short)f2bf(qb2.z); af[7] = (short)f2bf(qb2.w);
        f32x4 a0 = {0.f, 0.f, 0.f, 0.f}, a1 = {0.f, 0.f, 0.f, 0.f};
        a0 = __builtin_amdgcn_mfma_f32_16x16x32_bf16(af, bfr[0], a0, 0, 0, 0);
        a1 = __builtin_amdgcn_mfma_f32_16x16x32_bf16(af, bfr[1], a1, 0, 0, 0);
        #pragma unroll
        for (int r = 0; r < 4; ++r) {
            size_t trow = (size_t)b * NN + row0 + i * 16 + (lane >> 4) * 4 + r;
            qkv[trow * 768 + 256 + h * 32 + lr]      = a0[r];
            qkv[trow * 768 + 256 + h * 32 + 16 + lr] = a1[r];
        }
    }
}

// ---------------- domain gating ----------------
__global__ __launch_bounds__(256) void da_kernel(
    const float* __restrict__ dl, const float* __restrict__ w1,
    const float* __restrict__ b1, const float* __restrict__ w2,
    const float* __restrict__ b2, float* __restrict__ da)
{
    const int b = blockIdx.x, t = threadIdx.x;
    __shared__ float r[HID];
    __shared__ float raw[CC];
    if (t < HID) {
        float s = b1[t];
        #pragma unroll
        for (int k = 0; k < 4; ++k) s += dl[b * 4 + k] * w1[k * HID + t];
        r[t] = fmaxf(s, 0.f);
    }
    __syncthreads();
    float s = b2[t];
    for (int j = 0; j < HID; ++j) s += r[j] * w2[j * CC + t];
    raw[t] = s;
    __syncthreads();
    const int ch = t & 31;
    float m = -3.4e38f;
    #pragma unroll
    for (int hh = 0; hh < NH; ++hh) m = fmaxf(m, raw[hh * 32 + ch]);
    float ssum = 0.f;
    #pragma unroll
    for (int hh = 0; hh < NH; ++hh) ssum += __expf(raw[hh * 32 + ch] - m);
    da[b * CC + t] = __expf(raw[t] - m) / ssum;
}

// ---------------- combine: conv + fa + gating (paired channels) ------------
template<int KS, int KSLO>
__device__ __forceinline__ void comb_body(
    uint* vt, int c0,
    const float* __restrict__ wlo_base, const float* __restrict__ whi_base,
    const float* __restrict__ blo_base, const float* __restrict__ bhi_base,
    const float* __restrict__ qkv, const float* __restrict__ da,
    ushort* __restrict__ out)
{
    constexpr int R = KS / 2, OFF = R - KSLO / 2;
    const int hx = blockIdx.x & 1, y = blockIdx.y, b = blockIdx.z;
    const int x0 = hx * 28;
    const int t = threadIdx.x;
    const int p = t & 31;
    // stage v tile: KS rows x 34 cols, bf16 channel pairs
    for (int rr = 0; rr < KS; ++rr) {
        int gy = y + rr - R;
        const float* src = qkv + ((size_t)b * NN + gy * 56) * 768 + 512 + c0;
        for (int lc = t >> 5; lc < 34; lc += 8) {
            int gx = x0 + lc - 3;
            float vlo = 0.f, vhi = 0.f;
            if ((unsigned)gy < 56u && (unsigned)gx < 56u) {
                vlo = src[(size_t)gx * 768 + p];
                vhi = src[(size_t)gx * 768 + p + 32];
            }
            vt[(rr * 34 + lc) * 32 + p] = pk2(vlo, vhi);
        }
    }
    // packed weights (lo kernel zero-padded into KS x KS grid)
    uint wp[KS * KS];
    {
        const float* wl = wlo_base + p * (KSLO * KSLO);
        const float* wh = whi_base + p * (KS * KS);
        #pragma unroll
        for (int dy = 0; dy < KS; ++dy)
            #pragma unroll
            for (int dx = 0; dx < KS; ++dx) {
                float lo = 0.f;
                if (dy >= OFF && dy < OFF + KSLO && dx >= OFF && dx < OFF + KSLO)
                    lo = wl[(dy - OFF) * KSLO + (dx - OFF)];
                wp[dy * KS + dx] = pk2(lo, wh[dy * KS + dx]);
            }
    }
    const float blo = blo_base[p], bhi = bhi_base[p];
    const float dalo = da[b * CC + c0 + p], dahi = da[b * CC + c0 + 32 + p];
    __syncthreads();

    const int wv = t >> 6, th = (t >> 5) & 1;
    int txl[4]; float clo[4], chi[4];
    #pragma unroll
    for (int jj = 0; jj < 4; ++jj) {
        int j = wv + jj * 4; if (j > 13) j = 13;
        txl[jj] = 2 * j + th;
        clo[jj] = blo; chi[jj] = bhi;
    }
    #pragma unroll
    for (int dy = 0; dy < KS; ++dy)
        #pragma unroll
        for (int dx = 0; dx < KS; ++dx) {
            const uint wpk = wp[dy * KS + dx];
            const float wl = unlo(wpk), wh = unhi(wpk);
            #pragma unroll
            for (int jj = 0; jj < 4; ++jj) {
                uint vv = vt[(dy * 34 + txl[jj] + 3 - R + dx) * 32 + p];
                clo[jj] = fmaf(unlo(vv), wl, clo[jj]);
                chi[jj] = fmaf(unhi(vv), wh, chi[jj]);
            }
        }
    #pragma unroll
    for (int jj = 0; jj < 4; ++jj) {
        size_t tokg = (size_t)b * NN + y * 56 + x0 + txl[jj];
        const float* row = qkv + tokg * 768;
        float fal = row[256 + c0 + p], fah = row[256 + c0 + 32 + p];
        float ql = row[c0 + p], qh = row[c0 + 32 + p];
        out[tokg * CC + c0 + p]      = f2bf(dalo * (SCALE * fal + ql * clo[jj]));
        out[tokg * CC + c0 + 32 + p] = f2bf(dahi * (SCALE * fah + qh * chi[jj]));
    }
}

__global__ __launch_bounds__(256) void combine_kernel(
    const float* __restrict__ qkv, const float* __restrict__ da,
    const float* __restrict__ w3, const float* __restrict__ b3,
    const float* __restrict__ w5, const float* __restrict__ b5,
    const float* __restrict__ w7, const float* __restrict__ b7,
    ushort* __restrict__ out)
{
    __shared__ uint vt[7 * 34 * 32];
    switch (blockIdx.x >> 1) {
    case 0: comb_body<3,3>(vt, 0,   w3,           w3 + 32*9,  b3,      b3 + 32, qkv, da, out); break;
    case 1: comb_body<5,5>(vt, 64,  w5,           w5 + 32*25, b5,      b5 + 32, qkv, da, out); break;
    case 2: comb_body<7,5>(vt, 128, w5 + 64*25,   w7,         b5 + 64, b7,      qkv, da, out); break;
    default: comb_body<7,7>(vt, 192, w7 + 32*49,  w7 + 64*49, b7 + 32, b7 + 64, qkv, da, out); break;
    }
}

// ---------------- launch ----------------
extern "C" void kernel_launch(void* const* d_in, const int* in_sizes, int n_in,
                              void* d_out, int out_size, void* d_ws, size_t ws_size,
                              hipStream_t stream)
{
    const float* x       = (const float*)d_in[0];
    const float* dlab    = (const float*)d_in[1];
    const float* cpe_w   = (const float*)d_in[2];
    const float* cpe_b   = (const float*)d_in[3];
    const float* ln1_g   = (const float*)d_in[4];
    const float* ln1_b   = (const float*)d_in[5];
    const float* qkv_w   = (const float*)d_in[6];
    const float* proj_w  = (const float*)d_in[7];
    const float* proj_b  = (const float*)d_in[8];
    const float* dl_w1   = (const float*)d_in[9];
    const float* dl_b1   = (const float*)d_in[10];
    const float* dl_w2   = (const float*)d_in[11];
    const float* dl_b2   = (const float*)d_in[12];
    const float* crpe_w3 = (const float*)d_in[13];
    const float* crpe_b3 = (const float*)d_in[14];
    const float* crpe_w5 = (const float*)d_in[15];
    const float* crpe_b5 = (const float*)d_in[16];
    const float* crpe_w7 = (const float*)d_in[17];
    const float* crpe_b7 = (const float*)d_in[18];
    const float* ln2_g   = (const float*)d_in[19];
    const float* ln2_b   = (const float*)d_in[20];
    const float* fc1_w   = (const float*)d_in[21];
    const float* fc1_b   = (const float*)d_in[22];
    const float* fc2_w   = (const float*)d_in[23];
    const float* fc2_b   = (const float*)d_in[24];
    const int*   dptr    = (const int*)d_in[27];

    float* out = (float*)d_out;
    char* W = (char*)d_ws;
    size_t off = 0;
    float* x1 = (float*)(W + off);          off += (size_t)NT * CC * 4;   // f32 [NT,C]
    float* qkv = (float*)(W + off);                                        // f32 [NT,768]
    ushort* hidden = (ushort*)qkv;                                         // overlay: bf16 [NT,1024]
    off += (size_t)NT * 768 * 4;
    ushort* actbf = (ushort*)(W + off);     off += (size_t)NT * CC * 2;   // bf16 [NT,C]
    // overlay: kv partials live only between qkv-GEMM and fa, while actbf is dead
    float* partial = (float*)actbf;                    // 16*65536 f32 = 4 MB
    float* psum = partial + (size_t)16 * 65536;        // 32768 f32
    float* kvb = (float*)(W + off);         off += (size_t)65536 * 4;
    float* dab = (float*)(W + off);         off += (size_t)BB * CC * 4;
    float* pmax = (float*)(W + off);        off += (size_t)BB * 32 * CC * 4;
    float* cmax = (float*)(W + off);        off += (size_t)BB * CC * 4;
    ushort* wq  = (ushort*)(W + off);       off += (size_t)768 * 256 * 2;
    ushort* wp  = (ushort*)(W + off);       off += (size_t)256 * 256 * 2;
    ushort* w1t = (ushort*)(W + off);       off += (size_t)1024 * 256 * 2;
    ushort* w2t = (ushort*)(W + off);       off += (size_t)256 * 1024 * 2;

    // 0. weight transpose+cast (tiny)
    hipLaunchKernelGGL(wtrans_kernel, dim3(768), dim3(256), 0, stream, qkv_w, wq, 256, 768);
    hipLaunchKernelGGL(wtrans_kernel, dim3(256), dim3(256), 0, stream, proj_w, wp, 256, 256);
    hipLaunchKernelGGL(wtrans_kernel, dim3(1024), dim3(256), 0, stream, fc1_w, w1t, 256, 1024);
    hipLaunchKernelGGL(wtrans_kernel, dim3(1024), dim3(256), 0, stream, fc2_w, w2t, 1024, 256);
    // 1. CPE -> x1 (f32)
    hipLaunchKernelGGL(cpe_kernel, dim3(8, 56, 8), dim3(256), 0, stream, x, cpe_w, cpe_b, x1);
    // 2. domain gating
    hipLaunchKernelGGL(da_kernel, dim3(BB), dim3(256), 0, stream,
                       dlab, dl_w1, dl_b1, dl_w2, dl_b2, dab);
    // 3. LN1 -> actbf (bf16)
    hipLaunchKernelGGL(ln_kernel, dim3(NT / 4), dim3(256), 0, stream,
                       x1, ln1_g, ln1_b, dptr, actbf);
    // 4. qkv GEMM: [NT,256]bf16 @ [768,256]^T -> qkv f32
    hipLaunchKernelGGL(gemm_mfma<0>, dim3(768 / 128, NT / 128), dim3(256), 0, stream,
                       actbf, wq, nullptr, nullptr, (void*)qkv, NT, 768, 256);
    // 5. k column max (chunked) + reduce
    hipLaunchKernelGGL(kmax1_kernel, dim3(32, 8), dim3(256), 0, stream, qkv, pmax);
    hipLaunchKernelGGL(kmax2_kernel, dim3(8), dim3(256), 0, stream, pmax, cmax);
    // 6. kv partial sums + normalize
    hipLaunchKernelGGL(kvacc_kernel, dim3(16, 8, 8), dim3(256), 0, stream,
                       qkv, cmax, partial, psum);
    hipLaunchKernelGGL(kvnorm_kernel, dim3(256), dim3(256), 0, stream,
                       partial, psum, kvb);
    // 7. fa = q @ kv -> written into qkv's k-slot (k is dead now)
    hipLaunchKernelGGL(fa_kernel, dim3(7, 8, 8), dim3(256), 0, stream, qkv, kvb);
    // 8. combine (conv + fa + gating) -> actbf (bf16)
    hipLaunchKernelGGL(combine_kernel, dim3(8, 56, 8), dim3(256), 0, stream,
                       qkv, dab, crpe_w3, crpe_b3, crpe_w5, crpe_b5,
                       crpe_w7, crpe_b7, actbf);
    // 9. proj GEMM + bias + residual(x1) -> d_out f32
    hipLaunchKernelGGL(gemm_mfma<3>, dim3(256 / 128, NT / 128), dim3(256), 0, stream,
                       actbf, wp, proj_b, x1, (void*)out, NT, 256, 256);
    // 10. LN2 -> actbf (bf16)
    hipLaunchKernelGGL(ln_kernel, dim3(NT / 4), dim3(256), 0, stream,
                       out, ln2_g, ln2_b, dptr, actbf);
    // 11. fc1 + gelu -> hidden (bf16)
    hipLaunchKernelGGL(gemm_mfma<2>, dim3(1024 / 128, NT / 128), dim3(256), 0, stream,
                       actbf, w1t, fc1_b, nullptr, (void*)hidden, NT, 1024, 256);
    // 12. fc2 + bias + residual(d_out) -> d_out f32
    hipLaunchKernelGGL(gemm_mfma<3>, dim3(256 / 128, NT / 128), dim3(256), 0, stream,
                       hidden, w2t, fc2_b, out, (void*)out, NT, 256, 1024);
}